// Round 7
// baseline (321.586 us; speedup 1.0000x reference)
//
#include <hip/hip_runtime.h>

// Self-attention: B=4, S=2048, E=1024, H=16, D=64, causal, scale=1/32, fp32 I/O.
// Pipeline: cvt->bf16, QKV GEMM (MFMA), flash attention (MFMA), out GEMM.
// R3: attn — XOR-swizzled pad-free LDS (kills 8-way read conflicts), merged
// q-tile pair per block (one K/V staging loop serves both), exp2-domain
// softmax with defer-max (T13). log2e folded into Q scale in gemm_qkv.

#define E_DIM 1024
#define S_LEN 2048
#define BATCH 4
#define NHEAD 16
#define HDIM  64

using short8 = __attribute__((ext_vector_type(8))) short;
using f32x4  = __attribute__((ext_vector_type(4))) float;

__device__ inline unsigned short f2bf(float f) {
    unsigned int u = __builtin_bit_cast(unsigned int, f);
    u += 0x7FFFu + ((u >> 16) & 1u);   // round-to-nearest-even
    return (unsigned short)(u >> 16);
}

// ---------------- fp32 -> bf16 convert ----------------
__global__ __launch_bounds__(256) void cvt_f32_bf16(
        const float* __restrict__ src, unsigned short* __restrict__ dst, int n) {
    int i = (blockIdx.x * 256 + threadIdx.x) * 4;
    if (i >= n) return;
    float4 v = *reinterpret_cast<const float4*>(src + i);
    ushort4 o;
    o.x = f2bf(v.x); o.y = f2bf(v.y); o.z = f2bf(v.z); o.w = f2bf(v.w);
    *reinterpret_cast<ushort4*>(dst + i) = o;
}

// ---------------- QKV projection GEMM ----------------
__global__ __launch_bounds__(256) void gemm_qkv(
        const unsigned short* __restrict__ xb,
        const unsigned short* __restrict__ wb,
        unsigned short* __restrict__ qkv) {
    const int z = blockIdx.z;
    const unsigned short* Bw = wb + (size_t)z * (E_DIM * E_DIM);
    unsigned short* Out = qkv + (size_t)z * ((size_t)BATCH * NHEAD * S_LEN * HDIM);
    const int m0 = blockIdx.x * 128, n0 = blockIdx.y * 128;
    const int tid = threadIdx.x;
    const int lane = tid & 63, w = tid >> 6;
    const int wm = w >> 1, wn = w & 1;
    const int col = lane & 15, hi = lane >> 4;

    __shared__ __align__(16) unsigned short Alds[128 * 40];
    __shared__ __align__(16) unsigned short Blds[128 * 40];

    f32x4 acc[4][4] = {};

    for (int kt = 0; kt < E_DIM / 32; ++kt) {
        const int k0 = kt * 32;
#pragma unroll
        for (int i = 0; i < 2; ++i) {
            int c = tid + i * 256;
            int r = c >> 2, c8 = (c & 3) * 8;
            short8 va = *reinterpret_cast<const short8*>(xb + (size_t)(m0 + r) * E_DIM + k0 + c8);
            short8 vb = *reinterpret_cast<const short8*>(Bw + (size_t)(n0 + r) * E_DIM + k0 + c8);
            *reinterpret_cast<short8*>(&Alds[r * 40 + c8]) = va;
            *reinterpret_cast<short8*>(&Blds[r * 40 + c8]) = vb;
        }
        __syncthreads();
        short8 af[4], bf[4];
#pragma unroll
        for (int mt = 0; mt < 4; ++mt)
            af[mt] = *reinterpret_cast<const short8*>(&Alds[(wm * 64 + mt * 16 + col) * 40 + hi * 8]);
#pragma unroll
        for (int nt = 0; nt < 4; ++nt)
            bf[nt] = *reinterpret_cast<const short8*>(&Blds[(wn * 64 + nt * 16 + col) * 40 + hi * 8]);
#pragma unroll
        for (int mt = 0; mt < 4; ++mt)
#pragma unroll
            for (int nt = 0; nt < 4; ++nt)
                acc[mt][nt] = __builtin_amdgcn_mfma_f32_16x16x32_bf16(af[mt], bf[nt], acc[mt][nt], 0, 0, 0);
        __syncthreads();
    }

    // Q scale folds softmax 1/sqrt(1024) AND log2(e) (attn softmax in exp2 domain)
    const float scale = (z == 0) ? (0.03125f * 1.44269504f) : 1.0f;
#pragma unroll
    for (int mt = 0; mt < 4; ++mt) {
#pragma unroll
        for (int nt = 0; nt < 4; ++nt) {
#pragma unroll
            for (int b = 0; b < 4; ++b) {
                int m = m0 + wm * 64 + mt * 16 + hi * 4 + b;
                int n = n0 + wn * 64 + nt * 16 + col;
                int bidx = m >> 11, s = m & 2047;
                int h = n >> 6, d = n & 63;
                size_t off = (((size_t)(bidx * NHEAD + h)) * S_LEN + s) * HDIM + d;
                Out[off] = f2bf(acc[mt][nt][b] * scale);
            }
        }
    }
}

// ---------------- causal flash attention ----------------
// One tile-step for one q-tile state against the staged K/V tile.
__device__ __forceinline__ void attn_tile_step(
        bool diag, int q0, int kv0,
        const short8* qf, f32x4* acc, float* mrun, float* lrun,
        const unsigned short* __restrict__ Klds,
        const unsigned short* __restrict__ Vt,
        unsigned short* __restrict__ Pl,
        int col, int hi, int w) {
    // S = Q K^T  (scores already in exp2 domain via Q pre-scale)
    f32x4 s[4];
    __builtin_amdgcn_s_setprio(1);
#pragma unroll
    for (int kc = 0; kc < 4; ++kc) {
        const int row = kc * 16 + col;
        const int sw = (row & 7) << 3;
        const unsigned short* kb = Klds + row * 64;
        short8 kf0 = *reinterpret_cast<const short8*>(kb + ((hi * 8) ^ sw));
        short8 kf1 = *reinterpret_cast<const short8*>(kb + ((32 + hi * 8) ^ sw));
        f32x4 z4 = {0.f, 0.f, 0.f, 0.f};
        z4 = __builtin_amdgcn_mfma_f32_16x16x32_bf16(qf[0], kf0, z4, 0, 0, 0);
        s[kc] = __builtin_amdgcn_mfma_f32_16x16x32_bf16(qf[1], kf1, z4, 0, 0, 0);
    }
    __builtin_amdgcn_s_setprio(0);

    if (diag) { // causal mask on diagonal tile
#pragma unroll
        for (int kc = 0; kc < 4; ++kc) {
            int kg = kv0 + kc * 16 + col;
#pragma unroll
            for (int b = 0; b < 4; ++b) {
                int qg = q0 + w * 16 + hi * 4 + b;
                if (kg > qg) s[kc][b] = -INFINITY;
            }
        }
    }

    // per-row tile max (16-lane group reduce)
    float vb[4];
#pragma unroll
    for (int b = 0; b < 4; ++b) {
        float v = fmaxf(fmaxf(s[0][b], s[1][b]), fmaxf(s[2][b], s[3][b]));
        v = fmaxf(v, __shfl_xor(v, 1));
        v = fmaxf(v, __shfl_xor(v, 2));
        v = fmaxf(v, __shfl_xor(v, 4));
        v = fmaxf(v, __shfl_xor(v, 8));
        vb[b] = v;
    }
    // defer-max (T13): rescale only when some row grew > 11.5 (= 8 nats in exp2 domain)
    bool grow = (vb[0] > mrun[0] + 11.5f) || (vb[1] > mrun[1] + 11.5f) ||
                (vb[2] > mrun[2] + 11.5f) || (vb[3] > mrun[3] + 11.5f);
    if (__any(grow)) {
#pragma unroll
        for (int b = 0; b < 4; ++b) {
            float mnew = fmaxf(mrun[b], vb[b]);
            float fac = exp2f(mrun[b] - mnew);
            mrun[b] = mnew;
            lrun[b] *= fac;
#pragma unroll
            for (int dt = 0; dt < 4; ++dt) acc[dt][b] *= fac;
        }
    }
    // P = exp2(s - m), write to swizzled P-LDS (bf16)
#pragma unroll
    for (int kc = 0; kc < 4; ++kc) {
        const int c = kc * 16 + col;
#pragma unroll
        for (int b = 0; b < 4; ++b) {
            float p = exp2f(s[kc][b] - mrun[b]);
            lrun[b] += p;
            const int r = hi * 4 + b;
            Pl[r * 64 + (c ^ ((r & 7) << 3))] = f2bf(p);
        }
    }
    // P fragments (A-layout): lane reads P[row=col][k-chunk]
    const int psw = (col & 7) << 3;
    short8 pf0 = *reinterpret_cast<const short8*>(Pl + col * 64 + ((hi * 8) ^ psw));
    short8 pf1 = *reinterpret_cast<const short8*>(Pl + col * 64 + ((32 + hi * 8) ^ psw));

    // O += P V
    __builtin_amdgcn_s_setprio(1);
#pragma unroll
    for (int dt = 0; dt < 4; ++dt) {
        const int row = dt * 16 + col;
        const int sw = (row & 7) << 3;
        const unsigned short* vbp = Vt + row * 64;
        short8 vf0 = *reinterpret_cast<const short8*>(vbp + ((hi * 8) ^ sw));
        short8 vf1 = *reinterpret_cast<const short8*>(vbp + ((32 + hi * 8) ^ sw));
        acc[dt] = __builtin_amdgcn_mfma_f32_16x16x32_bf16(pf0, vf0, acc[dt], 0, 0, 0);
        acc[dt] = __builtin_amdgcn_mfma_f32_16x16x32_bf16(pf1, vf1, acc[dt], 0, 0, 0);
    }
    __builtin_amdgcn_s_setprio(0);
}

// Block owns q-tiles (p, 31-p); one K/V loop serves both (low range is subset).
__global__ __launch_bounds__(256, 4) void attn_fwd(
        const unsigned short* __restrict__ Q,
        const unsigned short* __restrict__ K,
        const unsigned short* __restrict__ V,
        unsigned short* __restrict__ Out) {
    const int x = blockIdx.x;                          // 0..15
    const int pair = (x & 1) ? (15 - (x >> 1)) : (x >> 1); // balance per-CU iter counts
    const int qt0 = pair, qt1 = 31 - pair;
    const int bh = blockIdx.y;
    const int b_idx = bh >> 4, h = bh & 15;
    const int tid = threadIdx.x, lane = tid & 63, w = tid >> 6;
    const int col = lane & 15, hi = lane >> 4;

    const unsigned short* Qb = Q + (size_t)bh * (S_LEN * HDIM);
    const unsigned short* Kb = K + (size_t)bh * (S_LEN * HDIM);
    const unsigned short* Vb = V + (size_t)bh * (S_LEN * HDIM);

    __shared__ __align__(16) unsigned short Klds[64 * 64];
    __shared__ __align__(16) unsigned short Vt[64 * 64];
    __shared__ __align__(16) unsigned short Plds[4][16 * 64];

    // Q fragments for both q-tiles
    short8 qf0[2], qf1[2];
    {
        const unsigned short* qr0 = Qb + (size_t)(qt0 * 64 + w * 16 + col) * HDIM;
        qf0[0] = *reinterpret_cast<const short8*>(qr0 + hi * 8);
        qf0[1] = *reinterpret_cast<const short8*>(qr0 + 32 + hi * 8);
        const unsigned short* qr1 = Qb + (size_t)(qt1 * 64 + w * 16 + col) * HDIM;
        qf1[0] = *reinterpret_cast<const short8*>(qr1 + hi * 8);
        qf1[1] = *reinterpret_cast<const short8*>(qr1 + 32 + hi * 8);
    }

    f32x4 acc0[4] = {}, acc1[4] = {};
    float m0[4], l0[4], m1[4], l1[4];
#pragma unroll
    for (int b = 0; b < 4; ++b) {
        m0[b] = -INFINITY; l0[b] = 0.f;
        m1[b] = -INFINITY; l1[b] = 0.f;
    }

    // staging indices
    const int kr = tid >> 3, kc8 = (tid & 7) * 8;     // K rows kr, kr+32
    const int ksw = kc8 ^ ((kr & 7) << 3);            // (kr+32)&7 == kr&7
    const int vr = tid & 63, vc8 = (tid >> 6) * 8;    // V row vr, d-chunks vc8, vc8+32

    // prefetch tile 0
    short8 pk0 = *reinterpret_cast<const short8*>(Kb + (size_t)kr * HDIM + kc8);
    short8 pk1 = *reinterpret_cast<const short8*>(Kb + (size_t)(32 + kr) * HDIM + kc8);
    short8 pv0 = *reinterpret_cast<const short8*>(Vb + (size_t)vr * HDIM + vc8);
    short8 pv1 = *reinterpret_cast<const short8*>(Vb + (size_t)vr * HDIM + vc8 + 32);

    for (int t = 0; t <= qt1; ++t) {
        const int kv0 = t * 64;
        __syncthreads();   // prior tile's LDS reads complete
        *reinterpret_cast<short8*>(&Klds[kr * 64 + ksw]) = pk0;
        *reinterpret_cast<short8*>(&Klds[(kr + 32) * 64 + ksw]) = pk1;
#pragma unroll
        for (int j = 0; j < 8; ++j) {
            const int d0 = vc8 + j;          // (d0+32)&7 == d0&7
            const int vsw = vr ^ ((d0 & 7) << 3);
            Vt[d0 * 64 + vsw]        = (unsigned short)pv0[j];
            Vt[(d0 + 32) * 64 + vsw] = (unsigned short)pv1[j];
        }
        if (t < qt1) { // prefetch next tile; latency hides under compute
            const int kn = kv0 + 64;
            pk0 = *reinterpret_cast<const short8*>(Kb + (size_t)(kn + kr) * HDIM + kc8);
            pk1 = *reinterpret_cast<const short8*>(Kb + (size_t)(kn + 32 + kr) * HDIM + kc8);
            pv0 = *reinterpret_cast<const short8*>(Vb + (size_t)(kn + vr) * HDIM + vc8);
            pv1 = *reinterpret_cast<const short8*>(Vb + (size_t)(kn + vr) * HDIM + vc8 + 32);
        }
        __syncthreads();   // staging visible

        if (t <= qt0)
            attn_tile_step(t == qt0, qt0 * 64, kv0, qf0, acc0, m0, l0,
                           Klds, Vt, &Plds[w][0], col, hi, w);
        attn_tile_step(t == qt1, qt1 * 64, kv0, qf1, acc1, m1, l1,
                       Klds, Vt, &Plds[w][0], col, hi, w);
    }

    // finalize both states
#pragma unroll
    for (int b = 0; b < 4; ++b) {
        float la = l0[b];
        la += __shfl_xor(la, 1); la += __shfl_xor(la, 2);
        la += __shfl_xor(la, 4); la += __shfl_xor(la, 8);
        float inva = 1.0f / la;
        int qga = qt0 * 64 + w * 16 + hi * 4 + b;
        float lb = l1[b];
        lb += __shfl_xor(lb, 1); lb += __shfl_xor(lb, 2);
        lb += __shfl_xor(lb, 4); lb += __shfl_xor(lb, 8);
        float invb = 1.0f / lb;
        int qgb = qt1 * 64 + w * 16 + hi * 4 + b;
#pragma unroll
        for (int dt = 0; dt < 4; ++dt) {
            size_t offa = ((size_t)(b_idx * S_LEN + qga)) * E_DIM + h * HDIM + dt * 16 + col;
            Out[offa] = f2bf(acc0[dt][b] * inva);
            size_t offb = ((size_t)(b_idx * S_LEN + qgb)) * E_DIM + h * HDIM + dt * 16 + col;
            Out[offb] = f2bf(acc1[dt][b] * invb);
        }
    }
}

// ---------------- output projection GEMM + bias ----------------
__global__ __launch_bounds__(256) void gemm_out(
        const unsigned short* __restrict__ Ab,
        const unsigned short* __restrict__ Bw,
        const float* __restrict__ bias,
        float* __restrict__ Out) {
    const int m0 = blockIdx.x * 128, n0 = blockIdx.y * 128;
    const int tid = threadIdx.x;
    const int lane = tid & 63, w = tid >> 6;
    const int wm = w >> 1, wn = w & 1;
    const int col = lane & 15, hi = lane >> 4;

    __shared__ __align__(16) unsigned short Alds[128 * 40];
    __shared__ __align__(16) unsigned short Blds[128 * 40];

    f32x4 acc[4][4] = {};

    for (int kt = 0; kt < E_DIM / 32; ++kt) {
        const int k0 = kt * 32;
#pragma unroll
        for (int i = 0; i < 2; ++i) {
            int c = tid + i * 256;
            int r = c >> 2, c8 = (c & 3) * 8;
            short8 va = *reinterpret_cast<const short8*>(Ab + (size_t)(m0 + r) * E_DIM + k0 + c8);
            short8 vb = *reinterpret_cast<const short8*>(Bw + (size_t)(n0 + r) * E_DIM + k0 + c8);
            *reinterpret_cast<short8*>(&Alds[r * 40 + c8]) = va;
            *reinterpret_cast<short8*>(&Blds[r * 40 + c8]) = vb;
        }
        __syncthreads();
        short8 af[4], bf[4];
#pragma unroll
        for (int mt = 0; mt < 4; ++mt)
            af[mt] = *reinterpret_cast<const short8*>(&Alds[(wm * 64 + mt * 16 + col) * 40 + hi * 8]);
#pragma unroll
        for (int nt = 0; nt < 4; ++nt)
            bf[nt] = *reinterpret_cast<const short8*>(&Blds[(wn * 64 + nt * 16 + col) * 40 + hi * 8]);
#pragma unroll
        for (int mt = 0; mt < 4; ++mt)
#pragma unroll
            for (int nt = 0; nt < 4; ++nt)
                acc[mt][nt] = __builtin_amdgcn_mfma_f32_16x16x32_bf16(af[mt], bf[nt], acc[mt][nt], 0, 0, 0);
        __syncthreads();
    }

#pragma unroll
    for (int mt = 0; mt < 4; ++mt) {
#pragma unroll
        for (int nt = 0; nt < 4; ++nt) {
#pragma unroll
            for (int b = 0; b < 4; ++b) {
                int m = m0 + wm * 64 + mt * 16 + hi * 4 + b;
                int n = n0 + wn * 64 + nt * 16 + col;
                Out[(size_t)m * E_DIM + n] = acc[mt][nt][b] + bias[n];
            }
        }
    }
}

extern "C" void kernel_launch(void* const* d_in, const int* in_sizes, int n_in,
                              void* d_out, int out_size, void* d_ws, size_t ws_size,
                              hipStream_t stream) {
    const float* x  = (const float*)d_in[0];
    const float* Wq = (const float*)d_in[1];
    const float* Wk = (const float*)d_in[2];
    const float* Wv = (const float*)d_in[3];
    const float* Wo = (const float*)d_in[4];
    const float* bo = (const float*)d_in[5];
    float* out = (float*)d_out;

    unsigned short* ws   = (unsigned short*)d_ws;
    unsigned short* xb   = ws;
    unsigned short* wb   = xb + (size_t)8192 * 1024;
    unsigned short* qkv  = wb + (size_t)4 * 1024 * 1024;
    unsigned short* attn = qkv + (size_t)3 * 8192 * 1024;

    cvt_f32_bf16<<<8192, 256, 0, stream>>>(x, xb, 8192 * 1024);
    cvt_f32_bf16<<<1024, 256, 0, stream>>>(Wq, wb, 1024 * 1024);
    cvt_f32_bf16<<<1024, 256, 0, stream>>>(Wk, wb + 1048576, 1024 * 1024);
    cvt_f32_bf16<<<1024, 256, 0, stream>>>(Wv, wb + 2 * 1048576, 1024 * 1024);
    cvt_f32_bf16<<<1024, 256, 0, stream>>>(Wo, wb + 3 * 1048576, 1024 * 1024);

    gemm_qkv<<<dim3(64, 8, 3), 256, 0, stream>>>(xb, wb, qkv);
    attn_fwd<<<dim3(16, 64), 256, 0, stream>>>(qkv, qkv + 8388608, qkv + 2 * 8388608, attn);
    gemm_out<<<dim3(64, 8), 256, 0, stream>>>(attn, wb + 3 * 1048576, bo, out);
}

// Round 8
// 235.858 us; speedup vs baseline: 1.3635x; 1.3635x over previous
//
#include <hip/hip_runtime.h>

// Self-attention: B=4, S=2048, E=1024, H=16, D=64, causal, scale=1/32, fp32 I/O.
// Pipeline: cvt->bf16, QKV GEMM (MFMA), flash attention (MFMA), out GEMM.
// R8: revert merged-pair (it spilled: WRITE_SIZE 49->236MB). Two sequential
// single-state q-tile passes (R2 structure, 127us) + keep verified wins:
// XOR-swizzled pad-free LDS (conflicts 9.7M->0), exp2 softmax + defer-max,
// register prefetch (T14), setprio (T5). log2e folded into Q scale.

#define E_DIM 1024
#define S_LEN 2048
#define BATCH 4
#define NHEAD 16
#define HDIM  64

using short8 = __attribute__((ext_vector_type(8))) short;
using f32x4  = __attribute__((ext_vector_type(4))) float;

__device__ inline unsigned short f2bf(float f) {
    unsigned int u = __builtin_bit_cast(unsigned int, f);
    u += 0x7FFFu + ((u >> 16) & 1u);   // round-to-nearest-even
    return (unsigned short)(u >> 16);
}

// ---------------- fp32 -> bf16 convert ----------------
__global__ __launch_bounds__(256) void cvt_f32_bf16(
        const float* __restrict__ src, unsigned short* __restrict__ dst, int n) {
    int i = (blockIdx.x * 256 + threadIdx.x) * 4;
    if (i >= n) return;
    float4 v = *reinterpret_cast<const float4*>(src + i);
    ushort4 o;
    o.x = f2bf(v.x); o.y = f2bf(v.y); o.z = f2bf(v.z); o.w = f2bf(v.w);
    *reinterpret_cast<ushort4*>(dst + i) = o;
}

// ---------------- QKV projection GEMM ----------------
__global__ __launch_bounds__(256) void gemm_qkv(
        const unsigned short* __restrict__ xb,
        const unsigned short* __restrict__ wb,
        unsigned short* __restrict__ qkv) {
    const int z = blockIdx.z;
    const unsigned short* Bw = wb + (size_t)z * (E_DIM * E_DIM);
    unsigned short* Out = qkv + (size_t)z * ((size_t)BATCH * NHEAD * S_LEN * HDIM);
    const int m0 = blockIdx.x * 128, n0 = blockIdx.y * 128;
    const int tid = threadIdx.x;
    const int lane = tid & 63, w = tid >> 6;
    const int wm = w >> 1, wn = w & 1;
    const int col = lane & 15, hi = lane >> 4;

    __shared__ __align__(16) unsigned short Alds[128 * 40];
    __shared__ __align__(16) unsigned short Blds[128 * 40];

    f32x4 acc[4][4] = {};

    for (int kt = 0; kt < E_DIM / 32; ++kt) {
        const int k0 = kt * 32;
#pragma unroll
        for (int i = 0; i < 2; ++i) {
            int c = tid + i * 256;
            int r = c >> 2, c8 = (c & 3) * 8;
            short8 va = *reinterpret_cast<const short8*>(xb + (size_t)(m0 + r) * E_DIM + k0 + c8);
            short8 vb = *reinterpret_cast<const short8*>(Bw + (size_t)(n0 + r) * E_DIM + k0 + c8);
            *reinterpret_cast<short8*>(&Alds[r * 40 + c8]) = va;
            *reinterpret_cast<short8*>(&Blds[r * 40 + c8]) = vb;
        }
        __syncthreads();
        short8 af[4], bf[4];
#pragma unroll
        for (int mt = 0; mt < 4; ++mt)
            af[mt] = *reinterpret_cast<const short8*>(&Alds[(wm * 64 + mt * 16 + col) * 40 + hi * 8]);
#pragma unroll
        for (int nt = 0; nt < 4; ++nt)
            bf[nt] = *reinterpret_cast<const short8*>(&Blds[(wn * 64 + nt * 16 + col) * 40 + hi * 8]);
#pragma unroll
        for (int mt = 0; mt < 4; ++mt)
#pragma unroll
            for (int nt = 0; nt < 4; ++nt)
                acc[mt][nt] = __builtin_amdgcn_mfma_f32_16x16x32_bf16(af[mt], bf[nt], acc[mt][nt], 0, 0, 0);
        __syncthreads();
    }

    // Q scale folds softmax 1/sqrt(1024) AND log2(e) (attn softmax in exp2 domain)
    const float scale = (z == 0) ? (0.03125f * 1.44269504f) : 1.0f;
#pragma unroll
    for (int mt = 0; mt < 4; ++mt) {
#pragma unroll
        for (int nt = 0; nt < 4; ++nt) {
#pragma unroll
            for (int b = 0; b < 4; ++b) {
                int m = m0 + wm * 64 + mt * 16 + hi * 4 + b;
                int n = n0 + wn * 64 + nt * 16 + col;
                int bidx = m >> 11, s = m & 2047;
                int h = n >> 6, d = n & 63;
                size_t off = (((size_t)(bidx * NHEAD + h)) * S_LEN + s) * HDIM + d;
                Out[off] = f2bf(acc[mt][nt][b] * scale);
            }
        }
    }
}

// ---------------- causal flash attention (one 64-row q-tile, single state) ----------------
__device__ __forceinline__ void attn_qtile(
        int qt, int b_idx, int h,
        const unsigned short* __restrict__ Qb,
        const unsigned short* __restrict__ Kb,
        const unsigned short* __restrict__ Vb,
        unsigned short* __restrict__ Out,
        unsigned short* Klds, unsigned short* Vt, unsigned short* Pl,
        int tid) {
    const int lane = tid & 63, w = tid >> 6;
    const int col = lane & 15, hi = lane >> 4;
    const int q0 = qt * 64;

    // staging indices
    const int kr = tid >> 3, kc8 = (tid & 7) * 8;     // K rows kr, kr+32
    const int ksw = kc8 ^ ((kr & 7) << 3);            // (kr+32)&7 == kr&7
    const int vr = tid & 63, vc8 = (tid >> 6) * 8;    // V row vr, d-chunks vc8, vc8+32

    // Q fragments (wave's 16 q-rows x 64 d), A-layout
    short8 qf[2];
    {
        const unsigned short* qrow = Qb + (size_t)(q0 + w * 16 + col) * HDIM;
        qf[0] = *reinterpret_cast<const short8*>(qrow + hi * 8);
        qf[1] = *reinterpret_cast<const short8*>(qrow + 32 + hi * 8);
    }

    f32x4 acc[4] = {};
    float mrun[4], lrun[4];
#pragma unroll
    for (int b = 0; b < 4; ++b) { mrun[b] = -INFINITY; lrun[b] = 0.f; }

    // prefetch tile 0
    short8 pk0 = *reinterpret_cast<const short8*>(Kb + (size_t)kr * HDIM + kc8);
    short8 pk1 = *reinterpret_cast<const short8*>(Kb + (size_t)(32 + kr) * HDIM + kc8);
    short8 pv0 = *reinterpret_cast<const short8*>(Vb + (size_t)vr * HDIM + vc8);
    short8 pv1 = *reinterpret_cast<const short8*>(Vb + (size_t)vr * HDIM + vc8 + 32);

    for (int t = 0; t <= qt; ++t) {
        const int kv0 = t * 64;
        __syncthreads();   // prior tile's LDS reads complete
        // K row-major swizzled; V transposed swizzled
        *reinterpret_cast<short8*>(&Klds[kr * 64 + ksw]) = pk0;
        *reinterpret_cast<short8*>(&Klds[(kr + 32) * 64 + ksw]) = pk1;
#pragma unroll
        for (int j = 0; j < 8; ++j) {
            const int d0 = vc8 + j;          // (d0+32)&7 == d0&7
            const int vsw = vr ^ ((d0 & 7) << 3);
            Vt[d0 * 64 + vsw]        = (unsigned short)pv0[j];
            Vt[(d0 + 32) * 64 + vsw] = (unsigned short)pv1[j];
        }
        if (t < qt) { // prefetch next tile; latency hides under compute
            const int kn = kv0 + 64;
            pk0 = *reinterpret_cast<const short8*>(Kb + (size_t)(kn + kr) * HDIM + kc8);
            pk1 = *reinterpret_cast<const short8*>(Kb + (size_t)(kn + 32 + kr) * HDIM + kc8);
            pv0 = *reinterpret_cast<const short8*>(Vb + (size_t)(kn + vr) * HDIM + vc8);
            pv1 = *reinterpret_cast<const short8*>(Vb + (size_t)(kn + vr) * HDIM + vc8 + 32);
        }
        __syncthreads();   // staging visible

        // S = Q K^T (scores in exp2 domain via Q pre-scale)
        f32x4 s[4];
        __builtin_amdgcn_s_setprio(1);
#pragma unroll
        for (int kc = 0; kc < 4; ++kc) {
            const int row = kc * 16 + col;
            const int sw = (row & 7) << 3;
            const unsigned short* kb = Klds + row * 64;
            short8 kf0 = *reinterpret_cast<const short8*>(kb + ((hi * 8) ^ sw));
            short8 kf1 = *reinterpret_cast<const short8*>(kb + ((32 + hi * 8) ^ sw));
            f32x4 z4 = {0.f, 0.f, 0.f, 0.f};
            z4 = __builtin_amdgcn_mfma_f32_16x16x32_bf16(qf[0], kf0, z4, 0, 0, 0);
            s[kc] = __builtin_amdgcn_mfma_f32_16x16x32_bf16(qf[1], kf1, z4, 0, 0, 0);
        }
        __builtin_amdgcn_s_setprio(0);

        if (t == qt) { // diagonal: causal mask
#pragma unroll
            for (int kc = 0; kc < 4; ++kc) {
                int kg = kv0 + kc * 16 + col;
#pragma unroll
                for (int b = 0; b < 4; ++b) {
                    int qg = q0 + w * 16 + hi * 4 + b;
                    if (kg > qg) s[kc][b] = -INFINITY;
                }
            }
        }

        // per-row tile max (16-lane group reduce)
        float vb[4];
#pragma unroll
        for (int b = 0; b < 4; ++b) {
            float v = fmaxf(fmaxf(s[0][b], s[1][b]), fmaxf(s[2][b], s[3][b]));
            v = fmaxf(v, __shfl_xor(v, 1));
            v = fmaxf(v, __shfl_xor(v, 2));
            v = fmaxf(v, __shfl_xor(v, 4));
            v = fmaxf(v, __shfl_xor(v, 8));
            vb[b] = v;
        }
        // defer-max (T13): rescale only when some row grew > 11.5 (=8 nats)
        bool grow = (vb[0] > mrun[0] + 11.5f) || (vb[1] > mrun[1] + 11.5f) ||
                    (vb[2] > mrun[2] + 11.5f) || (vb[3] > mrun[3] + 11.5f);
        if (__any(grow)) {
#pragma unroll
            for (int b = 0; b < 4; ++b) {
                float mnew = fmaxf(mrun[b], vb[b]);
                float fac = exp2f(mrun[b] - mnew);
                mrun[b] = mnew;
                lrun[b] *= fac;
#pragma unroll
                for (int dt = 0; dt < 4; ++dt) acc[dt][b] *= fac;
            }
        }
        // P = exp2(s - m), write to swizzled P-LDS (bf16)
#pragma unroll
        for (int kc = 0; kc < 4; ++kc) {
            const int c = kc * 16 + col;
#pragma unroll
            for (int b = 0; b < 4; ++b) {
                float p = exp2f(s[kc][b] - mrun[b]);
                lrun[b] += p;
                const int r = hi * 4 + b;
                Pl[r * 64 + (c ^ ((r & 7) << 3))] = f2bf(p);
            }
        }
        const int psw = (col & 7) << 3;
        short8 pf0 = *reinterpret_cast<const short8*>(Pl + col * 64 + ((hi * 8) ^ psw));
        short8 pf1 = *reinterpret_cast<const short8*>(Pl + col * 64 + ((32 + hi * 8) ^ psw));

        // O += P V
        __builtin_amdgcn_s_setprio(1);
#pragma unroll
        for (int dt = 0; dt < 4; ++dt) {
            const int row = dt * 16 + col;
            const int sw = (row & 7) << 3;
            const unsigned short* vbp = Vt + row * 64;
            short8 vf0 = *reinterpret_cast<const short8*>(vbp + ((hi * 8) ^ sw));
            short8 vf1 = *reinterpret_cast<const short8*>(vbp + ((32 + hi * 8) ^ sw));
            acc[dt] = __builtin_amdgcn_mfma_f32_16x16x32_bf16(pf0, vf0, acc[dt], 0, 0, 0);
            acc[dt] = __builtin_amdgcn_mfma_f32_16x16x32_bf16(pf1, vf1, acc[dt], 0, 0, 0);
        }
        __builtin_amdgcn_s_setprio(0);
    }

    // finalize
#pragma unroll
    for (int b = 0; b < 4; ++b) {
        float l = lrun[b];
        l += __shfl_xor(l, 1);
        l += __shfl_xor(l, 2);
        l += __shfl_xor(l, 4);
        l += __shfl_xor(l, 8);
        float inv = 1.0f / l;
        int qg = q0 + w * 16 + hi * 4 + b;
#pragma unroll
        for (int dt = 0; dt < 4; ++dt) {
            size_t off = ((size_t)(b_idx * S_LEN + qg)) * E_DIM + h * HDIM + dt * 16 + col;
            Out[off] = f2bf(acc[dt][b] * inv);
        }
    }
}

// paired q-tiles: block handles qt=pair and qt=31-pair -> uniform 33 tile-units
__global__ __launch_bounds__(256, 4) void attn_fwd(
        const unsigned short* __restrict__ Q,
        const unsigned short* __restrict__ K,
        const unsigned short* __restrict__ V,
        unsigned short* __restrict__ Out) {
    const int pair = blockIdx.x;  // 0..15
    const int bh = blockIdx.y;    // 0..63
    const int b_idx = bh >> 4, h = bh & 15;
    const int tid = threadIdx.x, w = tid >> 6;

    const unsigned short* Qb = Q + (size_t)bh * (S_LEN * HDIM);
    const unsigned short* Kb = K + (size_t)bh * (S_LEN * HDIM);
    const unsigned short* Vb = V + (size_t)bh * (S_LEN * HDIM);

    __shared__ __align__(16) unsigned short Klds[64 * 64];
    __shared__ __align__(16) unsigned short Vt[64 * 64];
    __shared__ __align__(16) unsigned short Plds[4][16 * 64];

    attn_qtile(pair, b_idx, h, Qb, Kb, Vb, Out, Klds, Vt, &Plds[w][0], tid);
    attn_qtile(31 - pair, b_idx, h, Qb, Kb, Vb, Out, Klds, Vt, &Plds[w][0], tid);
}

// ---------------- output projection GEMM + bias ----------------
__global__ __launch_bounds__(256) void gemm_out(
        const unsigned short* __restrict__ Ab,
        const unsigned short* __restrict__ Bw,
        const float* __restrict__ bias,
        float* __restrict__ Out) {
    const int m0 = blockIdx.x * 128, n0 = blockIdx.y * 128;
    const int tid = threadIdx.x;
    const int lane = tid & 63, w = tid >> 6;
    const int wm = w >> 1, wn = w & 1;
    const int col = lane & 15, hi = lane >> 4;

    __shared__ __align__(16) unsigned short Alds[128 * 40];
    __shared__ __align__(16) unsigned short Blds[128 * 40];

    f32x4 acc[4][4] = {};

    for (int kt = 0; kt < E_DIM / 32; ++kt) {
        const int k0 = kt * 32;
#pragma unroll
        for (int i = 0; i < 2; ++i) {
            int c = tid + i * 256;
            int r = c >> 2, c8 = (c & 3) * 8;
            short8 va = *reinterpret_cast<const short8*>(Ab + (size_t)(m0 + r) * E_DIM + k0 + c8);
            short8 vb = *reinterpret_cast<const short8*>(Bw + (size_t)(n0 + r) * E_DIM + k0 + c8);
            *reinterpret_cast<short8*>(&Alds[r * 40 + c8]) = va;
            *reinterpret_cast<short8*>(&Blds[r * 40 + c8]) = vb;
        }
        __syncthreads();
        short8 af[4], bf[4];
#pragma unroll
        for (int mt = 0; mt < 4; ++mt)
            af[mt] = *reinterpret_cast<const short8*>(&Alds[(wm * 64 + mt * 16 + col) * 40 + hi * 8]);
#pragma unroll
        for (int nt = 0; nt < 4; ++nt)
            bf[nt] = *reinterpret_cast<const short8*>(&Blds[(wn * 64 + nt * 16 + col) * 40 + hi * 8]);
#pragma unroll
        for (int mt = 0; mt < 4; ++mt)
#pragma unroll
            for (int nt = 0; nt < 4; ++nt)
                acc[mt][nt] = __builtin_amdgcn_mfma_f32_16x16x32_bf16(af[mt], bf[nt], acc[mt][nt], 0, 0, 0);
        __syncthreads();
    }

#pragma unroll
    for (int mt = 0; mt < 4; ++mt) {
#pragma unroll
        for (int nt = 0; nt < 4; ++nt) {
#pragma unroll
            for (int b = 0; b < 4; ++b) {
                int m = m0 + wm * 64 + mt * 16 + hi * 4 + b;
                int n = n0 + wn * 64 + nt * 16 + col;
                Out[(size_t)m * E_DIM + n] = acc[mt][nt][b] + bias[n];
            }
        }
    }
}

extern "C" void kernel_launch(void* const* d_in, const int* in_sizes, int n_in,
                              void* d_out, int out_size, void* d_ws, size_t ws_size,
                              hipStream_t stream) {
    const float* x  = (const float*)d_in[0];
    const float* Wq = (const float*)d_in[1];
    const float* Wk = (const float*)d_in[2];
    const float* Wv = (const float*)d_in[3];
    const float* Wo = (const float*)d_in[4];
    const float* bo = (const float*)d_in[5];
    float* out = (float*)d_out;

    unsigned short* ws   = (unsigned short*)d_ws;
    unsigned short* xb   = ws;
    unsigned short* wb   = xb + (size_t)8192 * 1024;
    unsigned short* qkv  = wb + (size_t)4 * 1024 * 1024;
    unsigned short* attn = qkv + (size_t)3 * 8192 * 1024;

    cvt_f32_bf16<<<8192, 256, 0, stream>>>(x, xb, 8192 * 1024);
    cvt_f32_bf16<<<1024, 256, 0, stream>>>(Wq, wb, 1024 * 1024);
    cvt_f32_bf16<<<1024, 256, 0, stream>>>(Wk, wb + 1048576, 1024 * 1024);
    cvt_f32_bf16<<<1024, 256, 0, stream>>>(Wv, wb + 2 * 1048576, 1024 * 1024);
    cvt_f32_bf16<<<1024, 256, 0, stream>>>(Wo, wb + 3 * 1048576, 1024 * 1024);

    gemm_qkv<<<dim3(64, 8, 3), 256, 0, stream>>>(xb, wb, qkv);
    attn_fwd<<<dim3(16, 64), 256, 0, stream>>>(qkv, qkv + 8388608, qkv + 2 * 8388608, attn);
    gemm_out<<<dim3(64, 8), 256, 0, stream>>>(attn, wb + 3 * 1048576, bo, out);
}

// Round 9
// 218.639 us; speedup vs baseline: 1.4709x; 1.0788x over previous
//
#include <hip/hip_runtime.h>

// Self-attention: B=4, S=2048, E=1024, H=16, D=64, causal, scale=1/32, fp32 I/O.
// Pipeline: cvt->bf16, QKV GEMM (MFMA), flash attention (MFMA), out GEMM.
// R9: attn is K/V-re-read memory-bound (528 stagings/bh, 8x XCD over-fetch).
// -> QBLK=128 (8 waves x 16 q-rows, 512 thr), stagings/bh 528->272
// -> XCD-packing swizzle: all 8 blocks of a bh share blockIdx%8 (same XCD L2)
// -> grid 512 = 2 blocks/CU exactly, uniform 34 steps (pair p,15-p sequential)
// Keeps R8-verified per-wave body: swizzled LDS, exp2+defer-max, prefetch, setprio.

#define E_DIM 1024
#define S_LEN 2048
#define BATCH 4
#define NHEAD 16
#define HDIM  64

using short8 = __attribute__((ext_vector_type(8))) short;
using f32x4  = __attribute__((ext_vector_type(4))) float;

__device__ inline unsigned short f2bf(float f) {
    unsigned int u = __builtin_bit_cast(unsigned int, f);
    u += 0x7FFFu + ((u >> 16) & 1u);   // round-to-nearest-even
    return (unsigned short)(u >> 16);
}

// ---------------- fp32 -> bf16 convert ----------------
__global__ __launch_bounds__(256) void cvt_f32_bf16(
        const float* __restrict__ src, unsigned short* __restrict__ dst, int n) {
    int i = (blockIdx.x * 256 + threadIdx.x) * 4;
    if (i >= n) return;
    float4 v = *reinterpret_cast<const float4*>(src + i);
    ushort4 o;
    o.x = f2bf(v.x); o.y = f2bf(v.y); o.z = f2bf(v.z); o.w = f2bf(v.w);
    *reinterpret_cast<ushort4*>(dst + i) = o;
}

// ---------------- QKV projection GEMM ----------------
__global__ __launch_bounds__(256) void gemm_qkv(
        const unsigned short* __restrict__ xb,
        const unsigned short* __restrict__ wb,
        unsigned short* __restrict__ qkv) {
    const int z = blockIdx.z;
    const unsigned short* Bw = wb + (size_t)z * (E_DIM * E_DIM);
    unsigned short* Out = qkv + (size_t)z * ((size_t)BATCH * NHEAD * S_LEN * HDIM);
    const int m0 = blockIdx.x * 128, n0 = blockIdx.y * 128;
    const int tid = threadIdx.x;
    const int lane = tid & 63, w = tid >> 6;
    const int wm = w >> 1, wn = w & 1;
    const int col = lane & 15, hi = lane >> 4;

    __shared__ __align__(16) unsigned short Alds[128 * 40];
    __shared__ __align__(16) unsigned short Blds[128 * 40];

    f32x4 acc[4][4] = {};

    for (int kt = 0; kt < E_DIM / 32; ++kt) {
        const int k0 = kt * 32;
#pragma unroll
        for (int i = 0; i < 2; ++i) {
            int c = tid + i * 256;
            int r = c >> 2, c8 = (c & 3) * 8;
            short8 va = *reinterpret_cast<const short8*>(xb + (size_t)(m0 + r) * E_DIM + k0 + c8);
            short8 vb = *reinterpret_cast<const short8*>(Bw + (size_t)(n0 + r) * E_DIM + k0 + c8);
            *reinterpret_cast<short8*>(&Alds[r * 40 + c8]) = va;
            *reinterpret_cast<short8*>(&Blds[r * 40 + c8]) = vb;
        }
        __syncthreads();
        short8 af[4], bf[4];
#pragma unroll
        for (int mt = 0; mt < 4; ++mt)
            af[mt] = *reinterpret_cast<const short8*>(&Alds[(wm * 64 + mt * 16 + col) * 40 + hi * 8]);
#pragma unroll
        for (int nt = 0; nt < 4; ++nt)
            bf[nt] = *reinterpret_cast<const short8*>(&Blds[(wn * 64 + nt * 16 + col) * 40 + hi * 8]);
#pragma unroll
        for (int mt = 0; mt < 4; ++mt)
#pragma unroll
            for (int nt = 0; nt < 4; ++nt)
                acc[mt][nt] = __builtin_amdgcn_mfma_f32_16x16x32_bf16(af[mt], bf[nt], acc[mt][nt], 0, 0, 0);
        __syncthreads();
    }

    // Q scale folds softmax 1/sqrt(1024) AND log2(e) (attn softmax in exp2 domain)
    const float scale = (z == 0) ? (0.03125f * 1.44269504f) : 1.0f;
#pragma unroll
    for (int mt = 0; mt < 4; ++mt) {
#pragma unroll
        for (int nt = 0; nt < 4; ++nt) {
#pragma unroll
            for (int b = 0; b < 4; ++b) {
                int m = m0 + wm * 64 + mt * 16 + hi * 4 + b;
                int n = n0 + wn * 64 + nt * 16 + col;
                int bidx = m >> 11, s = m & 2047;
                int h = n >> 6, d = n & 63;
                size_t off = (((size_t)(bidx * NHEAD + h)) * S_LEN + s) * HDIM + d;
                Out[off] = f2bf(acc[mt][nt][b] * scale);
            }
        }
    }
}

// ---------------- causal flash attention ----------------
// 512 threads = 8 waves; block covers 128-row q-tiles (p, 15-p) as two
// sequential single-state passes; KVBLK=64 staged once per step for all waves.
__global__ __launch_bounds__(512, 4) void attn_fwd(
        const unsigned short* __restrict__ Q,
        const unsigned short* __restrict__ K,
        const unsigned short* __restrict__ V,
        unsigned short* __restrict__ Out) {
    const int g = blockIdx.x;                 // 0..511
    const int p = g >> 6;                     // pair index 0..7
    const int bh = (g & 7) + ((g >> 3) & 7) * 8;  // all p-blocks of a bh share g%8 -> same XCD
    const int b_idx = bh >> 4, h = bh & 15;
    const int tid = threadIdx.x, lane = tid & 63, w = tid >> 6;  // w: 0..7
    const int col = lane & 15, hi = lane >> 4;

    const unsigned short* Qb = Q + (size_t)bh * (S_LEN * HDIM);
    const unsigned short* Kb = K + (size_t)bh * (S_LEN * HDIM);
    const unsigned short* Vb = V + (size_t)bh * (S_LEN * HDIM);

    __shared__ __align__(16) unsigned short Klds[64 * 64];
    __shared__ __align__(16) unsigned short Vt[64 * 64];
    __shared__ __align__(16) unsigned short Plds[8][16 * 64];
    unsigned short* Pl = &Plds[w][0];

    // staging indices: 512 threads, one short8 of K and one of V each
    const int kr = tid >> 3, kc8 = (tid & 7) * 8;   // K row kr, chunk kc8
    const int ksw = kc8 ^ ((kr & 7) << 3);
    const int vr = tid & 63, vc8 = (tid >> 6) * 8;  // V row vr, d-chunk vc8

#pragma unroll
    for (int pass = 0; pass < 2; ++pass) {
        const int qt = pass ? (15 - p) : p;    // 128-row q-tile index
        const int nt = 2 * qt + 2;             // 64-row kv tiles to stage
        const int q0 = qt * 128 + w * 16;      // wave's 16-row strip

        // Q fragments (A-layout)
        short8 qf0, qf1;
        {
            const unsigned short* qrow = Qb + (size_t)(q0 + col) * HDIM;
            qf0 = *reinterpret_cast<const short8*>(qrow + hi * 8);
            qf1 = *reinterpret_cast<const short8*>(qrow + 32 + hi * 8);
        }

        f32x4 acc[4] = {};
        float mrun[4], lrun[4];
#pragma unroll
        for (int b = 0; b < 4; ++b) { mrun[b] = -INFINITY; lrun[b] = 0.f; }

        // prefetch kv tile 0 (reads only; no LDS hazard)
        short8 pk = *reinterpret_cast<const short8*>(Kb + (size_t)kr * HDIM + kc8);
        short8 pv = *reinterpret_cast<const short8*>(Vb + (size_t)vr * HDIM + vc8);

        for (int t = 0; t < nt; ++t) {
            const int kv0 = t * 64;
            __syncthreads();   // prior step's LDS reads (and prior pass) complete
            *reinterpret_cast<short8*>(&Klds[kr * 64 + ksw]) = pk;
#pragma unroll
            for (int j = 0; j < 8; ++j) {
                const int d0 = vc8 + j;
                Vt[d0 * 64 + (vr ^ ((d0 & 7) << 3))] = (unsigned short)pv[j];
            }
            if (t < nt - 1) { // prefetch next tile; latency hides under compute
                const int kn = kv0 + 64;
                pk = *reinterpret_cast<const short8*>(Kb + (size_t)(kn + kr) * HDIM + kc8);
                pv = *reinterpret_cast<const short8*>(Vb + (size_t)(kn + vr) * HDIM + vc8);
            }
            __syncthreads();   // staging visible

            if (kv0 <= q0 + 15) {  // wave-uniform skip above the diagonal
                // S = Q K^T (scores in exp2 domain via Q pre-scale)
                f32x4 s[4];
                __builtin_amdgcn_s_setprio(1);
#pragma unroll
                for (int kc = 0; kc < 4; ++kc) {
                    const int row = kc * 16 + col;
                    const int sw = (row & 7) << 3;
                    const unsigned short* kb = Klds + row * 64;
                    short8 kf0 = *reinterpret_cast<const short8*>(kb + ((hi * 8) ^ sw));
                    short8 kf1 = *reinterpret_cast<const short8*>(kb + ((32 + hi * 8) ^ sw));
                    f32x4 z4 = {0.f, 0.f, 0.f, 0.f};
                    z4 = __builtin_amdgcn_mfma_f32_16x16x32_bf16(qf0, kf0, z4, 0, 0, 0);
                    s[kc] = __builtin_amdgcn_mfma_f32_16x16x32_bf16(qf1, kf1, z4, 0, 0, 0);
                }
                __builtin_amdgcn_s_setprio(0);

                if (kv0 + 63 > q0) { // diagonal-overlap: causal mask
#pragma unroll
                    for (int kc = 0; kc < 4; ++kc) {
                        int kg = kv0 + kc * 16 + col;
#pragma unroll
                        for (int b = 0; b < 4; ++b) {
                            int qg = q0 + hi * 4 + b;
                            if (kg > qg) s[kc][b] = -INFINITY;
                        }
                    }
                }

                // per-row tile max (16-lane group reduce)
                float vb[4];
#pragma unroll
                for (int b = 0; b < 4; ++b) {
                    float v = fmaxf(fmaxf(s[0][b], s[1][b]), fmaxf(s[2][b], s[3][b]));
                    v = fmaxf(v, __shfl_xor(v, 1));
                    v = fmaxf(v, __shfl_xor(v, 2));
                    v = fmaxf(v, __shfl_xor(v, 4));
                    v = fmaxf(v, __shfl_xor(v, 8));
                    vb[b] = v;
                }
                // defer-max (T13): rescale only when some row grew > 11.5 (=8 nats)
                bool grow = (vb[0] > mrun[0] + 11.5f) || (vb[1] > mrun[1] + 11.5f) ||
                            (vb[2] > mrun[2] + 11.5f) || (vb[3] > mrun[3] + 11.5f);
                if (__any(grow)) {
#pragma unroll
                    for (int b = 0; b < 4; ++b) {
                        float mnew = fmaxf(mrun[b], vb[b]);
                        float fac = exp2f(mrun[b] - mnew);
                        mrun[b] = mnew;
                        lrun[b] *= fac;
#pragma unroll
                        for (int dt = 0; dt < 4; ++dt) acc[dt][b] *= fac;
                    }
                }
                // P = exp2(s - m) -> swizzled per-wave P-LDS (bf16)
#pragma unroll
                for (int kc = 0; kc < 4; ++kc) {
                    const int c = kc * 16 + col;
#pragma unroll
                    for (int b = 0; b < 4; ++b) {
                        float pp = exp2f(s[kc][b] - mrun[b]);
                        lrun[b] += pp;
                        const int r = hi * 4 + b;
                        Pl[r * 64 + (c ^ ((r & 7) << 3))] = f2bf(pp);
                    }
                }
                const int psw = (col & 7) << 3;
                short8 pf0 = *reinterpret_cast<const short8*>(Pl + col * 64 + ((hi * 8) ^ psw));
                short8 pf1 = *reinterpret_cast<const short8*>(Pl + col * 64 + ((32 + hi * 8) ^ psw));

                // O += P V
                __builtin_amdgcn_s_setprio(1);
#pragma unroll
                for (int dt = 0; dt < 4; ++dt) {
                    const int row = dt * 16 + col;
                    const int sw = (row & 7) << 3;
                    const unsigned short* vbp = Vt + row * 64;
                    short8 vf0 = *reinterpret_cast<const short8*>(vbp + ((hi * 8) ^ sw));
                    short8 vf1 = *reinterpret_cast<const short8*>(vbp + ((32 + hi * 8) ^ sw));
                    acc[dt] = __builtin_amdgcn_mfma_f32_16x16x32_bf16(pf0, vf0, acc[dt], 0, 0, 0);
                    acc[dt] = __builtin_amdgcn_mfma_f32_16x16x32_bf16(pf1, vf1, acc[dt], 0, 0, 0);
                }
                __builtin_amdgcn_s_setprio(0);
            }
        }

        // finalize this pass
#pragma unroll
        for (int b = 0; b < 4; ++b) {
            float l = lrun[b];
            l += __shfl_xor(l, 1);
            l += __shfl_xor(l, 2);
            l += __shfl_xor(l, 4);
            l += __shfl_xor(l, 8);
            float inv = 1.0f / l;
            int qg = q0 + hi * 4 + b;
#pragma unroll
            for (int dt = 0; dt < 4; ++dt) {
                size_t off = ((size_t)(b_idx * S_LEN + qg)) * E_DIM + h * HDIM + dt * 16 + col;
                Out[off] = f2bf(acc[dt][b] * inv);
            }
        }
    }
}

// ---------------- output projection GEMM + bias ----------------
__global__ __launch_bounds__(256) void gemm_out(
        const unsigned short* __restrict__ Ab,
        const unsigned short* __restrict__ Bw,
        const float* __restrict__ bias,
        float* __restrict__ Out) {
    const int m0 = blockIdx.x * 128, n0 = blockIdx.y * 128;
    const int tid = threadIdx.x;
    const int lane = tid & 63, w = tid >> 6;
    const int wm = w >> 1, wn = w & 1;
    const int col = lane & 15, hi = lane >> 4;

    __shared__ __align__(16) unsigned short Alds[128 * 40];
    __shared__ __align__(16) unsigned short Blds[128 * 40];

    f32x4 acc[4][4] = {};

    for (int kt = 0; kt < E_DIM / 32; ++kt) {
        const int k0 = kt * 32;
#pragma unroll
        for (int i = 0; i < 2; ++i) {
            int c = tid + i * 256;
            int r = c >> 2, c8 = (c & 3) * 8;
            short8 va = *reinterpret_cast<const short8*>(Ab + (size_t)(m0 + r) * E_DIM + k0 + c8);
            short8 vb = *reinterpret_cast<const short8*>(Bw + (size_t)(n0 + r) * E_DIM + k0 + c8);
            *reinterpret_cast<short8*>(&Alds[r * 40 + c8]) = va;
            *reinterpret_cast<short8*>(&Blds[r * 40 + c8]) = vb;
        }
        __syncthreads();
        short8 af[4], bf[4];
#pragma unroll
        for (int mt = 0; mt < 4; ++mt)
            af[mt] = *reinterpret_cast<const short8*>(&Alds[(wm * 64 + mt * 16 + col) * 40 + hi * 8]);
#pragma unroll
        for (int nt = 0; nt < 4; ++nt)
            bf[nt] = *reinterpret_cast<const short8*>(&Blds[(wn * 64 + nt * 16 + col) * 40 + hi * 8]);
#pragma unroll
        for (int mt = 0; mt < 4; ++mt)
#pragma unroll
            for (int nt = 0; nt < 4; ++nt)
                acc[mt][nt] = __builtin_amdgcn_mfma_f32_16x16x32_bf16(af[mt], bf[nt], acc[mt][nt], 0, 0, 0);
        __syncthreads();
    }

#pragma unroll
    for (int mt = 0; mt < 4; ++mt) {
#pragma unroll
        for (int nt = 0; nt < 4; ++nt) {
#pragma unroll
            for (int b = 0; b < 4; ++b) {
                int m = m0 + wm * 64 + mt * 16 + hi * 4 + b;
                int n = n0 + wn * 64 + nt * 16 + col;
                Out[(size_t)m * E_DIM + n] = acc[mt][nt][b] + bias[n];
            }
        }
    }
}

extern "C" void kernel_launch(void* const* d_in, const int* in_sizes, int n_in,
                              void* d_out, int out_size, void* d_ws, size_t ws_size,
                              hipStream_t stream) {
    const float* x  = (const float*)d_in[0];
    const float* Wq = (const float*)d_in[1];
    const float* Wk = (const float*)d_in[2];
    const float* Wv = (const float*)d_in[3];
    const float* Wo = (const float*)d_in[4];
    const float* bo = (const float*)d_in[5];
    float* out = (float*)d_out;

    unsigned short* ws   = (unsigned short*)d_ws;
    unsigned short* xb   = ws;
    unsigned short* wb   = xb + (size_t)8192 * 1024;
    unsigned short* qkv  = wb + (size_t)4 * 1024 * 1024;
    unsigned short* attn = qkv + (size_t)3 * 8192 * 1024;

    cvt_f32_bf16<<<8192, 256, 0, stream>>>(x, xb, 8192 * 1024);
    cvt_f32_bf16<<<1024, 256, 0, stream>>>(Wq, wb, 1024 * 1024);
    cvt_f32_bf16<<<1024, 256, 0, stream>>>(Wk, wb + 1048576, 1024 * 1024);
    cvt_f32_bf16<<<1024, 256, 0, stream>>>(Wv, wb + 2 * 1048576, 1024 * 1024);
    cvt_f32_bf16<<<1024, 256, 0, stream>>>(Wo, wb + 3 * 1048576, 1024 * 1024);

    gemm_qkv<<<dim3(64, 8, 3), 256, 0, stream>>>(xb, wb, qkv);
    attn_fwd<<<512, 512, 0, stream>>>(qkv, qkv + 8388608, qkv + 2 * 8388608, attn);
    gemm_out<<<dim3(64, 8), 256, 0, stream>>>(attn, wb + 3 * 1048576, bo, out);
}

// Round 10
// 196.462 us; speedup vs baseline: 1.6369x; 1.1129x over previous
//
#include <hip/hip_runtime.h>

// Self-attention: B=4, S=2048, E=1024, H=16, D=64, causal, scale=1/32, fp32 I/O.
// Pipeline: cvt->bf16 (fused, 1 launch), QKV GEMM (MFMA + global_load_lds),
// flash attention (unchanged from R9: XCD-packed, QBLK=128, swizzled LDS,
// exp2+defer-max, prefetch, setprio), out GEMM (global_load_lds) + bias.
// R10: GEMMs ported to m97 structure — async global->LDS staging (width 16),
// linear [128][32] LDS tiles; cvt launches fused 5->1.

#define E_DIM 1024
#define S_LEN 2048
#define BATCH 4
#define NHEAD 16
#define HDIM  64

using short8 = __attribute__((ext_vector_type(8))) short;
using f32x4  = __attribute__((ext_vector_type(4))) float;

// async global->LDS, 16B per lane; lds dest = wave-uniform base + lane*16
#define GLD16(gp, lp) __builtin_amdgcn_global_load_lds( \
    (const __attribute__((address_space(1))) void*)(gp), \
    (__attribute__((address_space(3))) void*)(lp), 16, 0, 0)

__device__ inline unsigned short f2bf(float f) {
    unsigned int u = __builtin_bit_cast(unsigned int, f);
    u += 0x7FFFu + ((u >> 16) & 1u);   // round-to-nearest-even
    return (unsigned short)(u >> 16);
}

// ---------------- fused fp32 -> bf16 convert (x + 4 weights, one launch) ----------------
__global__ __launch_bounds__(256) void cvt_all(
        const float* __restrict__ x,  const float* __restrict__ wq,
        const float* __restrict__ wk, const float* __restrict__ wv,
        const float* __restrict__ wo,
        unsigned short* __restrict__ xb, unsigned short* __restrict__ wb) {
    const int bid = blockIdx.x;
    const float* src;
    unsigned short* dst;
    int blk;
    if (bid < 8192) { src = x; dst = xb; blk = bid; }
    else {
        const int wsel = (bid - 8192) >> 10;          // 0..3
        blk = (bid - 8192) & 1023;
        src = (wsel == 0) ? wq : (wsel == 1) ? wk : (wsel == 2) ? wv : wo;
        dst = wb + (size_t)wsel * 1048576;
    }
    const int i = (blk * 256 + threadIdx.x) * 4;
    float4 v = *reinterpret_cast<const float4*>(src + i);
    ushort4 o;
    o.x = f2bf(v.x); o.y = f2bf(v.y); o.z = f2bf(v.z); o.w = f2bf(v.w);
    *reinterpret_cast<ushort4*>(dst + i) = o;
}

// ---------------- QKV projection GEMM (global_load_lds staging) ----------------
__global__ __launch_bounds__(256) void gemm_qkv(
        const unsigned short* __restrict__ xb,
        const unsigned short* __restrict__ wb,
        unsigned short* __restrict__ qkv) {
    const int z = blockIdx.z;
    const unsigned short* Bw = wb + (size_t)z * (E_DIM * E_DIM);
    unsigned short* Out = qkv + (size_t)z * ((size_t)BATCH * NHEAD * S_LEN * HDIM);
    const int m0 = blockIdx.x * 128, n0 = blockIdx.y * 128;
    const int tid = threadIdx.x;
    const int lane = tid & 63, w = tid >> 6;
    const int wm = w >> 1, wn = w & 1;
    const int col = lane & 15, hi = lane >> 4;

    // linear [128][32] tiles; lane l of wave w owns LDS bytes (w*64+l)*16
    __shared__ __align__(16) unsigned short Alds[128 * 32];
    __shared__ __align__(16) unsigned short Blds[128 * 32];

    const int srow = tid >> 2;               // 0..63 (row within 64-row half)
    const int sc8  = (tid & 3) * 8;          // k-chunk
    const int wofs = w * 512;                // wave-uniform LDS base (elements)

    f32x4 acc[4][4] = {};

    for (int kt = 0; kt < E_DIM / 32; ++kt) {
        const int k0 = kt * 32;
        // issue async staging (A/B, two 64-row halves each)
        GLD16(xb + (size_t)(m0 + srow) * E_DIM + k0 + sc8,       &Alds[wofs]);
        GLD16(xb + (size_t)(m0 + 64 + srow) * E_DIM + k0 + sc8,  &Alds[2048 + wofs]);
        GLD16(Bw + (size_t)(n0 + srow) * E_DIM + k0 + sc8,       &Blds[wofs]);
        GLD16(Bw + (size_t)(n0 + 64 + srow) * E_DIM + k0 + sc8,  &Blds[2048 + wofs]);
        __syncthreads();   // drains vmcnt -> staged data visible
        short8 af[4], bf[4];
#pragma unroll
        for (int mt = 0; mt < 4; ++mt)
            af[mt] = *reinterpret_cast<const short8*>(&Alds[(wm * 64 + mt * 16 + col) * 32 + hi * 8]);
#pragma unroll
        for (int nt = 0; nt < 4; ++nt)
            bf[nt] = *reinterpret_cast<const short8*>(&Blds[(wn * 64 + nt * 16 + col) * 32 + hi * 8]);
#pragma unroll
        for (int mt = 0; mt < 4; ++mt)
#pragma unroll
            for (int nt = 0; nt < 4; ++nt)
                acc[mt][nt] = __builtin_amdgcn_mfma_f32_16x16x32_bf16(af[mt], bf[nt], acc[mt][nt], 0, 0, 0);
        __syncthreads();   // reads done before next iter's staging writes
    }

    // Q scale folds softmax 1/sqrt(1024) AND log2(e) (attn softmax in exp2 domain)
    const float scale = (z == 0) ? (0.03125f * 1.44269504f) : 1.0f;
#pragma unroll
    for (int mt = 0; mt < 4; ++mt) {
#pragma unroll
        for (int nt = 0; nt < 4; ++nt) {
#pragma unroll
            for (int b = 0; b < 4; ++b) {
                int m = m0 + wm * 64 + mt * 16 + hi * 4 + b;
                int n = n0 + wn * 64 + nt * 16 + col;
                int bidx = m >> 11, s = m & 2047;
                int h = n >> 6, d = n & 63;
                size_t off = (((size_t)(bidx * NHEAD + h)) * S_LEN + s) * HDIM + d;
                Out[off] = f2bf(acc[mt][nt][b] * scale);
            }
        }
    }
}

// ---------------- causal flash attention (unchanged from R9) ----------------
// 512 threads = 8 waves; block covers 128-row q-tiles (p, 15-p) as two
// sequential single-state passes; KVBLK=64 staged once per step for all waves.
__global__ __launch_bounds__(512, 4) void attn_fwd(
        const unsigned short* __restrict__ Q,
        const unsigned short* __restrict__ K,
        const unsigned short* __restrict__ V,
        unsigned short* __restrict__ Out) {
    const int g = blockIdx.x;                 // 0..511
    const int p = g >> 6;                     // pair index 0..7
    const int bh = (g & 7) + ((g >> 3) & 7) * 8;  // all p-blocks of a bh share g%8 -> same XCD
    const int b_idx = bh >> 4, h = bh & 15;
    const int tid = threadIdx.x, lane = tid & 63, w = tid >> 6;  // w: 0..7
    const int col = lane & 15, hi = lane >> 4;

    const unsigned short* Qb = Q + (size_t)bh * (S_LEN * HDIM);
    const unsigned short* Kb = K + (size_t)bh * (S_LEN * HDIM);
    const unsigned short* Vb = V + (size_t)bh * (S_LEN * HDIM);

    __shared__ __align__(16) unsigned short Klds[64 * 64];
    __shared__ __align__(16) unsigned short Vt[64 * 64];
    __shared__ __align__(16) unsigned short Plds[8][16 * 64];
    unsigned short* Pl = &Plds[w][0];

    // staging indices: 512 threads, one short8 of K and one of V each
    const int kr = tid >> 3, kc8 = (tid & 7) * 8;   // K row kr, chunk kc8
    const int ksw = kc8 ^ ((kr & 7) << 3);
    const int vr = tid & 63, vc8 = (tid >> 6) * 8;  // V row vr, d-chunk vc8

#pragma unroll
    for (int pass = 0; pass < 2; ++pass) {
        const int qt = pass ? (15 - p) : p;    // 128-row q-tile index
        const int nt = 2 * qt + 2;             // 64-row kv tiles to stage
        const int q0 = qt * 128 + w * 16;      // wave's 16-row strip

        // Q fragments (A-layout)
        short8 qf0, qf1;
        {
            const unsigned short* qrow = Qb + (size_t)(q0 + col) * HDIM;
            qf0 = *reinterpret_cast<const short8*>(qrow + hi * 8);
            qf1 = *reinterpret_cast<const short8*>(qrow + 32 + hi * 8);
        }

        f32x4 acc[4] = {};
        float mrun[4], lrun[4];
#pragma unroll
        for (int b = 0; b < 4; ++b) { mrun[b] = -INFINITY; lrun[b] = 0.f; }

        // prefetch kv tile 0 (reads only; no LDS hazard)
        short8 pk = *reinterpret_cast<const short8*>(Kb + (size_t)kr * HDIM + kc8);
        short8 pv = *reinterpret_cast<const short8*>(Vb + (size_t)vr * HDIM + vc8);

        for (int t = 0; t < nt; ++t) {
            const int kv0 = t * 64;
            __syncthreads();   // prior step's LDS reads (and prior pass) complete
            *reinterpret_cast<short8*>(&Klds[kr * 64 + ksw]) = pk;
#pragma unroll
            for (int j = 0; j < 8; ++j) {
                const int d0 = vc8 + j;
                Vt[d0 * 64 + (vr ^ ((d0 & 7) << 3))] = (unsigned short)pv[j];
            }
            if (t < nt - 1) { // prefetch next tile; latency hides under compute
                const int kn = kv0 + 64;
                pk = *reinterpret_cast<const short8*>(Kb + (size_t)(kn + kr) * HDIM + kc8);
                pv = *reinterpret_cast<const short8*>(Vb + (size_t)(kn + vr) * HDIM + vc8);
            }
            __syncthreads();   // staging visible

            if (kv0 <= q0 + 15) {  // wave-uniform skip above the diagonal
                // S = Q K^T (scores in exp2 domain via Q pre-scale)
                f32x4 s[4];
                __builtin_amdgcn_s_setprio(1);
#pragma unroll
                for (int kc = 0; kc < 4; ++kc) {
                    const int row = kc * 16 + col;
                    const int sw = (row & 7) << 3;
                    const unsigned short* kb = Klds + row * 64;
                    short8 kf0 = *reinterpret_cast<const short8*>(kb + ((hi * 8) ^ sw));
                    short8 kf1 = *reinterpret_cast<const short8*>(kb + ((32 + hi * 8) ^ sw));
                    f32x4 z4 = {0.f, 0.f, 0.f, 0.f};
                    z4 = __builtin_amdgcn_mfma_f32_16x16x32_bf16(qf0, kf0, z4, 0, 0, 0);
                    s[kc] = __builtin_amdgcn_mfma_f32_16x16x32_bf16(qf1, kf1, z4, 0, 0, 0);
                }
                __builtin_amdgcn_s_setprio(0);

                if (kv0 + 63 > q0) { // diagonal-overlap: causal mask
#pragma unroll
                    for (int kc = 0; kc < 4; ++kc) {
                        int kg = kv0 + kc * 16 + col;
#pragma unroll
                        for (int b = 0; b < 4; ++b) {
                            int qg = q0 + hi * 4 + b;
                            if (kg > qg) s[kc][b] = -INFINITY;
                        }
                    }
                }

                // per-row tile max (16-lane group reduce)
                float vb[4];
#pragma unroll
                for (int b = 0; b < 4; ++b) {
                    float v = fmaxf(fmaxf(s[0][b], s[1][b]), fmaxf(s[2][b], s[3][b]));
                    v = fmaxf(v, __shfl_xor(v, 1));
                    v = fmaxf(v, __shfl_xor(v, 2));
                    v = fmaxf(v, __shfl_xor(v, 4));
                    v = fmaxf(v, __shfl_xor(v, 8));
                    vb[b] = v;
                }
                // defer-max (T13): rescale only when some row grew > 11.5 (=8 nats)
                bool grow = (vb[0] > mrun[0] + 11.5f) || (vb[1] > mrun[1] + 11.5f) ||
                            (vb[2] > mrun[2] + 11.5f) || (vb[3] > mrun[3] + 11.5f);
                if (__any(grow)) {
#pragma unroll
                    for (int b = 0; b < 4; ++b) {
                        float mnew = fmaxf(mrun[b], vb[b]);
                        float fac = exp2f(mrun[b] - mnew);
                        mrun[b] = mnew;
                        lrun[b] *= fac;
#pragma unroll
                        for (int dt = 0; dt < 4; ++dt) acc[dt][b] *= fac;
                    }
                }
                // P = exp2(s - m) -> swizzled per-wave P-LDS (bf16)
#pragma unroll
                for (int kc = 0; kc < 4; ++kc) {
                    const int c = kc * 16 + col;
#pragma unroll
                    for (int b = 0; b < 4; ++b) {
                        float pp = exp2f(s[kc][b] - mrun[b]);
                        lrun[b] += pp;
                        const int r = hi * 4 + b;
                        Pl[r * 64 + (c ^ ((r & 7) << 3))] = f2bf(pp);
                    }
                }
                const int psw = (col & 7) << 3;
                short8 pf0 = *reinterpret_cast<const short8*>(Pl + col * 64 + ((hi * 8) ^ psw));
                short8 pf1 = *reinterpret_cast<const short8*>(Pl + col * 64 + ((32 + hi * 8) ^ psw));

                // O += P V
                __builtin_amdgcn_s_setprio(1);
#pragma unroll
                for (int dt = 0; dt < 4; ++dt) {
                    const int row = dt * 16 + col;
                    const int sw = (row & 7) << 3;
                    const unsigned short* vbp = Vt + row * 64;
                    short8 vf0 = *reinterpret_cast<const short8*>(vbp + ((hi * 8) ^ sw));
                    short8 vf1 = *reinterpret_cast<const short8*>(vbp + ((32 + hi * 8) ^ sw));
                    acc[dt] = __builtin_amdgcn_mfma_f32_16x16x32_bf16(pf0, vf0, acc[dt], 0, 0, 0);
                    acc[dt] = __builtin_amdgcn_mfma_f32_16x16x32_bf16(pf1, vf1, acc[dt], 0, 0, 0);
                }
                __builtin_amdgcn_s_setprio(0);
            }
        }

        // finalize this pass
#pragma unroll
        for (int b = 0; b < 4; ++b) {
            float l = lrun[b];
            l += __shfl_xor(l, 1);
            l += __shfl_xor(l, 2);
            l += __shfl_xor(l, 4);
            l += __shfl_xor(l, 8);
            float inv = 1.0f / l;
            int qg = q0 + hi * 4 + b;
#pragma unroll
            for (int dt = 0; dt < 4; ++dt) {
                size_t off = ((size_t)(b_idx * S_LEN + qg)) * E_DIM + h * HDIM + dt * 16 + col;
                Out[off] = f2bf(acc[dt][b] * inv);
            }
        }
    }
}

// ---------------- output projection GEMM + bias (global_load_lds staging) ----------------
__global__ __launch_bounds__(256) void gemm_out(
        const unsigned short* __restrict__ Ab,
        const unsigned short* __restrict__ Bw,
        const float* __restrict__ bias,
        float* __restrict__ Out) {
    const int m0 = blockIdx.x * 128, n0 = blockIdx.y * 128;
    const int tid = threadIdx.x;
    const int lane = tid & 63, w = tid >> 6;
    const int wm = w >> 1, wn = w & 1;
    const int col = lane & 15, hi = lane >> 4;

    __shared__ __align__(16) unsigned short Alds[128 * 32];
    __shared__ __align__(16) unsigned short Blds[128 * 32];

    const int srow = tid >> 2;
    const int sc8  = (tid & 3) * 8;
    const int wofs = w * 512;

    f32x4 acc[4][4] = {};

    for (int kt = 0; kt < E_DIM / 32; ++kt) {
        const int k0 = kt * 32;
        GLD16(Ab + (size_t)(m0 + srow) * E_DIM + k0 + sc8,       &Alds[wofs]);
        GLD16(Ab + (size_t)(m0 + 64 + srow) * E_DIM + k0 + sc8,  &Alds[2048 + wofs]);
        GLD16(Bw + (size_t)(n0 + srow) * E_DIM + k0 + sc8,       &Blds[wofs]);
        GLD16(Bw + (size_t)(n0 + 64 + srow) * E_DIM + k0 + sc8,  &Blds[2048 + wofs]);
        __syncthreads();
        short8 af[4], bf[4];
#pragma unroll
        for (int mt = 0; mt < 4; ++mt)
            af[mt] = *reinterpret_cast<const short8*>(&Alds[(wm * 64 + mt * 16 + col) * 32 + hi * 8]);
#pragma unroll
        for (int nt = 0; nt < 4; ++nt)
            bf[nt] = *reinterpret_cast<const short8*>(&Blds[(wn * 64 + nt * 16 + col) * 32 + hi * 8]);
#pragma unroll
        for (int mt = 0; mt < 4; ++mt)
#pragma unroll
            for (int nt = 0; nt < 4; ++nt)
                acc[mt][nt] = __builtin_amdgcn_mfma_f32_16x16x32_bf16(af[mt], bf[nt], acc[mt][nt], 0, 0, 0);
        __syncthreads();
    }

#pragma unroll
    for (int mt = 0; mt < 4; ++mt) {
#pragma unroll
        for (int nt = 0; nt < 4; ++nt) {
#pragma unroll
            for (int b = 0; b < 4; ++b) {
                int m = m0 + wm * 64 + mt * 16 + hi * 4 + b;
                int n = n0 + wn * 64 + nt * 16 + col;
                Out[(size_t)m * E_DIM + n] = acc[mt][nt][b] + bias[n];
            }
        }
    }
}

extern "C" void kernel_launch(void* const* d_in, const int* in_sizes, int n_in,
                              void* d_out, int out_size, void* d_ws, size_t ws_size,
                              hipStream_t stream) {
    const float* x  = (const float*)d_in[0];
    const float* Wq = (const float*)d_in[1];
    const float* Wk = (const float*)d_in[2];
    const float* Wv = (const float*)d_in[3];
    const float* Wo = (const float*)d_in[4];
    const float* bo = (const float*)d_in[5];
    float* out = (float*)d_out;

    unsigned short* ws   = (unsigned short*)d_ws;
    unsigned short* xb   = ws;
    unsigned short* wb   = xb + (size_t)8192 * 1024;
    unsigned short* qkv  = wb + (size_t)4 * 1024 * 1024;
    unsigned short* attn = qkv + (size_t)3 * 8192 * 1024;

    cvt_all<<<12288, 256, 0, stream>>>(x, Wq, Wk, Wv, Wo, xb, wb);
    gemm_qkv<<<dim3(64, 8, 3), 256, 0, stream>>>(xb, wb, qkv);
    attn_fwd<<<512, 512, 0, stream>>>(qkv, qkv + 8388608, qkv + 2 * 8388608, attn);
    gemm_out<<<dim3(64, 8), 256, 0, stream>>>(attn, wb + 3 * 1048576, bo, out);
}